// Round 3
// baseline (6008.562 us; speedup 1.0000x reference)
//
#include <hip/hip_runtime.h>
#include <hip/hip_bf16.h>

// ScalarBorn: 4th-order FD scalar wave + Born scattering with CPML, MI355X.
// Grid: 400x400 + PAD(22) = 444x444, NS=4 shots, NT=300 steps.
// State in __device__ globals; f32 internally. Input/output dtype (f32 vs
// bf16) is detected AT RUNTIME on-device: reading true-bf16 v at even
// indices gives ~[1500,2500]; reading f32 data's mantissa halves gives
// garbage. Round-1/2 NaNs are consistent with inputs actually being f32.

constexpr int NYX  = 400;
constexpr int NS   = 4;
constexpr int NREC = 100;
constexpr int NT   = 300;
constexpr int PAD  = 22;
constexpr int NP   = 444;
constexpr int NP2  = NP * NP;          // 197136
constexpr int SNP2 = NS * NP2;         // 788544
constexpr float DT    = 0.0005f;
constexpr float INVH  = 0.2f;          // 1/DX
constexpr float INVH2 = 0.04f;         // 1/DX^2
constexpr float C1A = 1.0f / 12.0f;
constexpr float C1B = 2.0f / 3.0f;
constexpr float C2A = -1.0f / 12.0f;
constexpr float C2B = 4.0f / 3.0f;
constexpr float C2C = -2.5f;

// state slots: 0 bw0, 1 bw1, 2 pyb, 3 pxb, 4 zyb, 5 zxb,
//              6 sw0, 7 sw1, 8 pys, 9 pxs, 10 zys, 11 zxs
__device__ __align__(16) float g_state[12][SNP2];   // ~37.9 MB
__device__ float g_v2dt2[NP2];
__device__ float g_bscale[NP2];
__device__ float g_pa[NP];
__device__ float g_pb[NP];
__device__ float g_fbg[NT * NS];
__device__ float g_fsc[NT * NS];
__device__ int   g_spos[2 * NS];
__device__ int   g_mode;               // 1 = bf16 inputs/outputs, 0 = f32

__device__ __forceinline__ int clampi(int v, int lo, int hi) {
    return v < lo ? lo : (v > hi ? hi : v);
}
__device__ __forceinline__ float in_ld(const void* p, int i) {
    if (g_mode) return __bfloat162float(((const __hip_bfloat16*)p)[i]);
    return ((const float*)p)[i];
}
__device__ __forceinline__ void out_st(void* p, int i, float v) {
    if (g_mode) ((__hip_bfloat16*)p)[i] = __float2bfloat16(v);
    else        ((float*)p)[i] = v;
}
__device__ __forceinline__ float ld(const float* w, int y, int x) {
    if ((unsigned)y >= (unsigned)NP || (unsigned)x >= (unsigned)NP) return 0.f;
    return w[y * NP + x];
}

__global__ void detect_mode(const void* vptr) {
    if (threadIdx.x == 0 && blockIdx.x == 0) {
        const __hip_bfloat16* p = (const __hip_bfloat16*)vptr;
        int ok = 1;
        for (int i = 0; i < 32; i += 2) {            // even indices: garbage if f32
            float f = __bfloat162float(p[i]);
            if (!(f >= 1000.f && f <= 3000.f)) ok = 0;
        }
        g_mode = ok;
    }
}

__global__ void zero_state() {
    int i = blockIdx.x * blockDim.x + threadIdx.x;
    if (i < 12 * SNP2 / 4) {
        float4* p = (float4*)&g_state[0][0];
        p[i] = make_float4(0.f, 0.f, 0.f, 0.f);
    }
}

__global__ void prep_pad(const void* __restrict__ v, const void* __restrict__ sc) {
    int i = blockIdx.x * blockDim.x + threadIdx.x;
    if (i >= NP2) return;
    int y = i / NP, x = i % NP;
    int vy = clampi(y - PAD, 0, NYX - 1);
    int vx = clampi(x - PAD, 0, NYX - 1);
    float vv = in_ld(v, vy * NYX + vx);
    float vd = vv * DT;
    g_v2dt2[i] = vd * vd;
    float s = 0.f;
    if (y >= PAD && y < PAD + NYX && x >= PAD && x < PAD + NYX)
        s = in_ld(sc, (y - PAD) * NYX + (x - PAD));
    g_bscale[i] = 2.f * vv * s * DT * DT;
    if (i < NP) {
        float fi = (float)i;
        float f1 = fminf(fmaxf((22.f - fi) * 0.05f, 0.f), 1.f);
        float f2 = fminf(fmaxf((fi - 421.f) * 0.05f, 0.f), 1.f);
        float frac = fmaxf(f1, f2);
        float sigma = 259.0408229f * frac * frac;   // 3*VMAX*ln(1000)/(2*PML*DX)
        const float alpha = 78.53981634f;           // pi*25
        float a = expf(-(sigma + alpha) * DT);
        g_pa[i] = a;
        g_pb[i] = (sigma > 0.f) ? sigma / (sigma + alpha) * (a - 1.f) : 0.f;
    }
}

__global__ void prep_src(const void* __restrict__ amp, const int* __restrict__ sloc,
                         const void* __restrict__ v, const void* __restrict__ sc) {
    int i = blockIdx.x * blockDim.x + threadIdx.x;
    if (i >= NT * NS) return;
    int s = i % NS, t = i / NS;
    int ly = clampi(sloc[s * 2 + 0], 0, NYX - 1);
    int lx = clampi(sloc[s * 2 + 1], 0, NYX - 1);
    float a  = in_ld(amp, s * NT + t);
    float vv = in_ld(v,  ly * NYX + lx);
    float ss = in_ld(sc, ly * NYX + lx);
    g_fbg[i] = -a * vv * vv * DT * DT;           // i == t*NS + s
    g_fsc[i] = -2.f * a * vv * ss * DT * DT;
    if (i < NS) {
        g_spos[2 * i]     = ly + PAD;
        g_spos[2 * i + 1] = lx + PAD;
    }
}

// pass1: psi updates (PML frame only: pb==0 exactly in interior) + record t-1
__global__ void __launch_bounds__(448)
pass1(int t, int trec,
      const int* __restrict__ rloc, const int* __restrict__ rbloc,
      void* __restrict__ out) {
    int x = threadIdx.x;
    int y = blockIdx.y;
    int s = blockIdx.z;
    const float* wb = g_state[t & 1];          // current bg field
    const float* ws = g_state[6 + (t & 1)];    // current scattered field
    if (trec >= 0 && y == 0 && x < 2 * NREC) {
        int r = x % NREC;
        bool isbg = x < NREC;
        const int* rl = isbg ? rbloc : rloc;
        int ry = clampi(rl[(s * NREC + r) * 2 + 0], 0, NYX - 1) + PAD;
        int rx = clampi(rl[(s * NREC + r) * 2 + 1], 0, NYX - 1) + PAD;
        const float* w = isbg ? wb : ws;
        float val = w[s * NP2 + ry * NP + rx];
        int base = isbg ? (2 * SNP2) : (2 * SNP2 + NS * NREC * NT);
        out_st(out, base + (s * NREC + r) * NT + trec, val);
    }
    if (x >= NP) return;
    float by = g_pb[y], bx = g_pb[x];
    if (by == 0.f && bx == 0.f) return;        // psi stays exactly 0 in interior
    const float* w0b = wb + s * NP2;
    const float* w0s = ws + s * NP2;
    int idx = s * NP2 + y * NP + x;
    if (by != 0.f) {
        float ay = g_pa[y];
        float db = (C1A * ld(w0b, y - 2, x) - C1B * ld(w0b, y - 1, x)
                  + C1B * ld(w0b, y + 1, x) - C1A * ld(w0b, y + 2, x)) * INVH;
        float ds = (C1A * ld(w0s, y - 2, x) - C1B * ld(w0s, y - 1, x)
                  + C1B * ld(w0s, y + 1, x) - C1A * ld(w0s, y + 2, x)) * INVH;
        g_state[2][idx] = ay * g_state[2][idx] + by * db;   // pyb
        g_state[8][idx] = ay * g_state[8][idx] + by * ds;   // pys
    }
    if (bx != 0.f) {
        float ax = g_pa[x];
        float db = (C1A * ld(w0b, y, x - 2) - C1B * ld(w0b, y, x - 1)
                  + C1B * ld(w0b, y, x + 1) - C1A * ld(w0b, y, x + 2)) * INVH;
        float ds = (C1A * ld(w0s, y, x - 2) - C1B * ld(w0s, y, x - 1)
                  + C1B * ld(w0s, y, x + 1) - C1A * ld(w0s, y, x + 2)) * INVH;
        g_state[3][idx] = ax * g_state[3][idx] + bx * db;   // pxb
        g_state[9][idx] = ax * g_state[9][idx] + bx * ds;   // pxs
    }
}

// pass2: d2 stencils, dpsi, zeta update, lap, leapfrog + source inject
__global__ void __launch_bounds__(448)
pass2(int t) {
    int x = threadIdx.x;
    if (x >= NP) return;
    int y = blockIdx.y, s = blockIdx.z;
    const float* wcb = g_state[t & 1];
    float*       wpb = g_state[1 - (t & 1)];
    const float* wcs = g_state[6 + (t & 1)];
    float*       wps = g_state[7 - (t & 1)];
    int yx  = y * NP + x;
    int idx = s * NP2 + yx;
    const float* wb0 = wcb + s * NP2;
    const float* ws0 = wcs + s * NP2;

    float wc_b = wb0[yx];
    float wc_s = ws0[yx];
    float d2y_b = (C2A * (ld(wb0, y - 2, x) + ld(wb0, y + 2, x))
                 + C2B * (ld(wb0, y - 1, x) + ld(wb0, y + 1, x)) + C2C * wc_b) * INVH2;
    float d2x_b = (C2A * (ld(wb0, y, x - 2) + ld(wb0, y, x + 2))
                 + C2B * (ld(wb0, y, x - 1) + ld(wb0, y, x + 1)) + C2C * wc_b) * INVH2;
    float d2y_s = (C2A * (ld(ws0, y - 2, x) + ld(ws0, y + 2, x))
                 + C2B * (ld(ws0, y - 1, x) + ld(ws0, y + 1, x)) + C2C * wc_s) * INVH2;
    float d2x_s = (C2A * (ld(ws0, y, x - 2) + ld(ws0, y, x + 2))
                 + C2B * (ld(ws0, y, x - 1) + ld(ws0, y, x + 1)) + C2C * wc_s) * INVH2;

    float dpy_b = 0.f, dpy_s = 0.f, dpx_b = 0.f, dpx_s = 0.f;
    if (y <= 23 || y >= 420) {       // psiy nonzero only rows <=21, >=422
        const float* p0b = g_state[2] + s * NP2;
        const float* p0s = g_state[8] + s * NP2;
        dpy_b = (C1A * ld(p0b, y - 2, x) - C1B * ld(p0b, y - 1, x)
               + C1B * ld(p0b, y + 1, x) - C1A * ld(p0b, y + 2, x)) * INVH;
        dpy_s = (C1A * ld(p0s, y - 2, x) - C1B * ld(p0s, y - 1, x)
               + C1B * ld(p0s, y + 1, x) - C1A * ld(p0s, y + 2, x)) * INVH;
    }
    if (x <= 23 || x >= 420) {
        const float* p0b = g_state[3] + s * NP2;
        const float* p0s = g_state[9] + s * NP2;
        dpx_b = (C1A * ld(p0b, y, x - 2) - C1B * ld(p0b, y, x - 1)
               + C1B * ld(p0b, y, x + 1) - C1A * ld(p0b, y, x + 2)) * INVH;
        dpx_s = (C1A * ld(p0s, y, x - 2) - C1B * ld(p0s, y, x - 1)
               + C1B * ld(p0s, y, x + 1) - C1A * ld(p0s, y, x + 2)) * INVH;
    }

    float zy_b = 0.f, zy_s = 0.f, zx_b = 0.f, zx_s = 0.f;
    float by = g_pb[y], bx = g_pb[x];
    if (by != 0.f) {
        float ay = g_pa[y];
        zy_b = ay * g_state[4][idx] + by * (d2y_b + dpy_b);  g_state[4][idx] = zy_b;
        zy_s = ay * g_state[10][idx] + by * (d2y_s + dpy_s); g_state[10][idx] = zy_s;
    }
    if (bx != 0.f) {
        float ax = g_pa[x];
        zx_b = ax * g_state[5][idx] + bx * (d2x_b + dpx_b);  g_state[5][idx] = zx_b;
        zx_s = ax * g_state[11][idx] + bx * (d2x_s + dpx_s); g_state[11][idx] = zx_s;
    }

    float lap_b = d2y_b + d2x_b + dpy_b + dpx_b + zy_b + zx_b;
    float lap_s = d2y_s + d2x_s + dpy_s + dpx_s + zy_s + zx_s;
    float v2 = g_v2dt2[yx];
    float wn_b = v2 * lap_b + 2.f * wc_b - wpb[idx];
    float wn_s = v2 * lap_s + 2.f * wc_s - wps[idx] + g_bscale[yx] * lap_b;
    if (y == g_spos[2 * s] && x == g_spos[2 * s + 1]) {
        wn_b += g_fbg[t * NS + s];
        wn_s += g_fsc[t * NS + s];
    }
    wpb[idx] = wn_b;
    wps[idx] = wn_s;
}

__global__ void finalize(const int* __restrict__ rloc, const int* __restrict__ rbloc,
                         void* __restrict__ out) {
    int i = blockIdx.x * blockDim.x + threadIdx.x;
    const float* wb0 = g_state[0];   // NT even: newest bg field in slot 0
    const float* ws0 = g_state[6];
    if (i < SNP2) {
        out_st(out, i,        wb0[i]);
        out_st(out, SNP2 + i, ws0[i]);
    }
    if (i < 2 * NS * NREC) {         // record last step (t = NT-1)
        bool isbg = i < NS * NREC;
        int k = isbg ? i : i - NS * NREC;
        int s = k / NREC, r = k % NREC;
        const int* rl = isbg ? rbloc : rloc;
        int ry = clampi(rl[(s * NREC + r) * 2 + 0], 0, NYX - 1) + PAD;
        int rx = clampi(rl[(s * NREC + r) * 2 + 1], 0, NYX - 1) + PAD;
        const float* w = isbg ? wb0 : ws0;
        float val = w[s * NP2 + ry * NP + rx];
        int base = isbg ? (2 * SNP2) : (2 * SNP2 + NS * NREC * NT);
        out_st(out, base + (s * NREC + r) * NT + (NT - 1), val);
    }
}

extern "C" void kernel_launch(void* const* d_in, const int* in_sizes, int n_in,
                              void* d_out, int out_size, void* d_ws, size_t ws_size,
                              hipStream_t stream) {
    const void* v   = d_in[0];
    const void* sc  = d_in[1];
    const void* amp = d_in[2];
    const int* sloc  = (const int*)d_in[3];
    const int* rloc  = (const int*)d_in[4];   // receiver_locations (scattered)
    const int* rbloc = (const int*)d_in[5];   // bg_receiver_locations

    detect_mode<<<1, 64, 0, stream>>>(v);
    zero_state<<<(12 * SNP2 / 4 + 255) / 256, 256, 0, stream>>>();
    prep_pad<<<(NP2 + 255) / 256, 256, 0, stream>>>(v, sc);
    prep_src<<<(NT * NS + 255) / 256, 256, 0, stream>>>(amp, sloc, v, sc);

    dim3 grid(1, NP, NS);
    for (int t = 0; t < NT; ++t) {
        pass1<<<grid, 448, 0, stream>>>(t, t - 1, rloc, rbloc, d_out);
        pass2<<<grid, 448, 0, stream>>>(t);
    }
    finalize<<<(SNP2 + 255) / 256, 256, 0, stream>>>(rloc, rbloc, d_out);
}